// Round 2
// 246.486 us; speedup vs baseline: 1.0979x; 1.0979x over previous
//
#include <hip/hip_runtime.h>
#include <cstdint>
#include <cstddef>
#include <cfloat>

// Problem constants (match reference)
static constexpr int BATCH = 32;
static constexpr int KJ    = 17;   // heat channels (joints)
static constexpr int LL    = 19;   // limbs
static constexpr int HH    = 160;
static constexpr int WW    = 160;
static constexpr int PPK   = 30;   // top-k peaks
static constexpr int SS    = 10;   // samples along limb
static constexpr int HW    = HH * WW;
static constexpr int CGW   = WW / 4;        // 40 float4 cells per row
static constexpr int CAP   = 4096;          // full candidate capacity (fallback)
static constexpr int NPAIR = PPK * PPK;     // 900
static constexpr int HALFP = NPAIR / 2;     // 450 active threads in conn
// 0.995: E[#hi per channel] ~= 25600*(1-0.995^9)/9 ~= 125 (min over 544 ch ~89 >> 30);
// per strip E ~= 31, SHICAP=192 is ~ +29 sigma. Fallback path keeps exactness for any data.
#define HITHR 0.995f

// split-peaks workspace
static constexpr int NSTR   = 4;            // strips per channel
static constexpr int SROWS  = HH / NSTR;    // 40 rows
static constexpr int SHICAP = 192;          // hi keys per strip
static constexpr int NCH    = BATCH * KJ;   // 544
static constexpr size_t WS_KEYS_BYTES = (size_t)NCH * NSTR * SHICAP * 8;
static constexpr size_t WS_CNT_BYTES  = (size_t)NCH * NSTR * 4;
static constexpr size_t WS_NEED = WS_KEYS_BYTES + WS_CNT_BYTES;

// conn quarter-plane staging
static constexpr int QROWS = 40;
static constexpr int QCNT  = QROWS * WW;    // 6400 floats = 25.6 KB
static constexpr int QF4   = QCNT / 4;

__constant__ int d_ska[LL] = {15,13,16,14,11,5,6,5,5,6,7,8,1,0,0,1,2,3,4};
__constant__ int d_skb[LL] = {13,11,14,12,12,11,12,6,7,8,9,10,2,1,2,3,4,5,6};
__constant__ float d_ts[SS] = {
    0.0f,
    (float)(1.0/9.0), (float)(2.0/9.0), (float)(3.0/9.0),
    (float)(4.0/9.0), (float)(5.0/9.0), (float)(6.0/9.0),
    (float)(7.0/9.0), (float)(8.0/9.0),
    1.0f
};

__device__ __forceinline__ float max3f(float a, float b, float c) {
    return fmaxf(fmaxf(a, b), c);
}
__device__ __forceinline__ unsigned long long umax64(unsigned long long a, unsigned long long b) {
    return a > b ? a : b;
}
__device__ __forceinline__ void async_copy16(const float4* gsrc_lane, float4* lds_wave_base) {
    __builtin_amdgcn_global_load_lds(
        (const __attribute__((address_space(1))) void*)gsrc_lane,
        (__attribute__((address_space(3))) void*)lds_wave_base,
        16, 0, 0);
}

// ---------------------------------------------------------------------------
// K1: hi-candidate strip scan. One block per (ch,strip); 256 threads.
// Tests ONLY v > HITHR local maxima (wave-uniform skip when no lane has a
// hi center; at 0.995 ~28% of waves skip). Appends keys to a <=192-entry
// LDS list, dumps to ws.
// ---------------------------------------------------------------------------
__global__ __launch_bounds__(256) void peaks_scan_hi(const float* __restrict__ heat,
                                                     unsigned long long* __restrict__ wsk,
                                                     int* __restrict__ wsc)
{
    const int blk   = blockIdx.x;           // ch*4 + strip
    const int ch    = blk >> 2;
    const int strip = blk & 3;
    const int y0    = strip * SROWS;
    const float* hp = heat + (size_t)ch * HW;

    __shared__ unsigned long long hik[SHICAP];
    __shared__ int hcnt;

    const int tid  = threadIdx.x;
    const int lane = tid & 63;
    const unsigned long long ltmask = ((unsigned long long)1 << lane) - 1ull;

    if (tid == 0) hcnt = 0;
    __syncthreads();

    for (int cell = tid; cell < SROWS * CGW; cell += 256) {
        int ly = cell / CGW;
        int cg = cell - ly * CGW;
        int y  = y0 + ly;
        int x0 = cg * 4;
        const float* rc = hp + y * WW + x0;
        float4 vc = *(const float4*)rc;

        bool h_any = (vc.x > HITHR) || (vc.y > HITHR) || (vc.z > HITHR) || (vc.w > HITHR);
        bool h0 = false, h1 = false, h2 = false, h3 = false;
        if (__any(h_any ? 1 : 0)) {          // wave-uniform skip
            int yu = (y > 0) ? y - 1 : 0;
            int yd = (y < HH - 1) ? y + 1 : HH - 1;
            const float* ru = hp + yu * WW + x0;
            const float* rd = hp + yd * WW + x0;
            float4 vu = *(const float4*)ru;
            float4 vd = *(const float4*)rd;
            int offL = (x0 > 0) ? -1 : 0;
            int offR = (x0 + 4 < WW) ? 4 : 3;
            float lc  = rc[offL], lu  = ru[offL], ld  = rd[offL];
            float rcx = rc[offR], rux = ru[offR], rdx = rd[offR];

            float mu0 = max3f(lu, vu.x, vu.y), mu1 = max3f(vu.x, vu.y, vu.z);
            float mu2 = max3f(vu.y, vu.z, vu.w), mu3 = max3f(vu.z, vu.w, rux);
            float mc0 = max3f(lc, vc.x, vc.y), mc1 = max3f(vc.x, vc.y, vc.z);
            float mc2 = max3f(vc.y, vc.z, vc.w), mc3 = max3f(vc.z, vc.w, rcx);
            float md0 = max3f(ld, vd.x, vd.y), md1 = max3f(vd.x, vd.y, vd.z);
            float md2 = max3f(vd.y, vd.z, vd.w), md3 = max3f(vd.z, vd.w, rdx);

            float nm0 = max3f(mu0, mc0, md0);
            float nm1 = max3f(mu1, mc1, md1);
            float nm2 = max3f(mu2, mc2, md2);
            float nm3 = max3f(mu3, mc3, md3);

            h0 = (vc.x == nm0) && (vc.x > HITHR);
            h1 = (vc.y == nm1) && (vc.y > HITHR);
            h2 = (vc.z == nm2) && (vc.z > HITHR);
            h3 = (vc.w == nm3) && (vc.w > HITHR);
        }
        unsigned long long b0 = __ballot(h0);
        unsigned long long b1 = __ballot(h1);
        unsigned long long b2 = __ballot(h2);
        unsigned long long b3 = __ballot(h3);
        int c0 = __popcll(b0), c1 = __popcll(b1), c2 = __popcll(b2), c3 = __popcll(b3);
        int tot = c0 + c1 + c2 + c3;
        if (tot == 0) continue;
        int base = 0;
        if (lane == 0) base = atomicAdd(&hcnt, tot);
        base = __shfl(base, 0);

        int idx0 = y * WW + x0;
        if (h0) { int s = base + __popcll(b0 & ltmask); if (s < SHICAP)
            hik[s] = ((unsigned long long)__float_as_uint(vc.x) << 32) | (unsigned long long)(0xFFFFFFFFu - (unsigned)(idx0 + 0)); }
        if (h1) { int s = base + c0 + __popcll(b1 & ltmask); if (s < SHICAP)
            hik[s] = ((unsigned long long)__float_as_uint(vc.y) << 32) | (unsigned long long)(0xFFFFFFFFu - (unsigned)(idx0 + 1)); }
        if (h2) { int s = base + c0 + c1 + __popcll(b2 & ltmask); if (s < SHICAP)
            hik[s] = ((unsigned long long)__float_as_uint(vc.z) << 32) | (unsigned long long)(0xFFFFFFFFu - (unsigned)(idx0 + 2)); }
        if (h3) { int s = base + c0 + c1 + c2 + __popcll(b3 & ltmask); if (s < SHICAP)
            hik[s] = ((unsigned long long)__float_as_uint(vc.w) << 32) | (unsigned long long)(0xFFFFFFFFu - (unsigned)(idx0 + 3)); }
    }
    __syncthreads();

    if (tid == 0) wsc[blk] = hcnt;                       // raw count (overflow detectable)
    const int n = (hcnt < SHICAP) ? hcnt : SHICAP;
    for (int i = tid; i < n; i += 256)
        wsk[(size_t)blk * SHICAP + i] = hik[i];
}

// ---------------------------------------------------------------------------
// K2: selection + subpixel refine + emit. One block of 256 per channel.
// Fast path (all strip counts <=192 and total >=30): compact keys into LDS,
// rank-select: each thread reads all n keys (LDS broadcast), rank =
// #strictly-greater; rank<30 writes sel[rank]. Exact: keys unique; >=30 keys
// above HITHR => global top-30 is entirely above HITHR.
// Fallback (rare, exactness): full >0.1 rescan + butterfly selection.
// ---------------------------------------------------------------------------
__global__ __launch_bounds__(256, 4) void peaks_select(const float* __restrict__ heat,
                                                       const unsigned long long* __restrict__ wsk,
                                                       const int* __restrict__ wsc,
                                                       float* __restrict__ out)
{
    const int ch = blockIdx.x;
    const float* hp = heat + (size_t)ch * HW;

    __shared__ unsigned long long keys[CAP];            // 32 KB (fast path uses <=768)
    __shared__ unsigned long long sel4[4 * PPK];
    __shared__ unsigned long long sel[PPK];
    __shared__ int cnt;

    const int tid  = threadIdx.x;
    const int lane = tid & 63;
    const int wave = tid >> 6;
    const unsigned long long ltmask = ((unsigned long long)1 << lane) - 1ull;

    const int c0 = wsc[ch * 4 + 0];
    const int c1 = wsc[ch * 4 + 1];
    const int c2 = wsc[ch * 4 + 2];
    const int c3 = wsc[ch * 4 + 3];
    const bool ok = (c0 <= SHICAP) && (c1 <= SHICAP) && (c2 <= SHICAP) && (c3 <= SHICAP);
    const int n = c0 + c1 + c2 + c3;

    if (tid == 0) cnt = 0;

    if (ok && n >= PPK) {
        // ---- FAST PATH ----
        const int off1 = c0, off2 = c0 + c1, off3 = c0 + c1 + c2;
        for (int i = tid; i < c0; i += 256) keys[i]        = wsk[(size_t)(ch * 4 + 0) * SHICAP + i];
        for (int i = tid; i < c1; i += 256) keys[off1 + i] = wsk[(size_t)(ch * 4 + 1) * SHICAP + i];
        for (int i = tid; i < c2; i += 256) keys[off2 + i] = wsk[(size_t)(ch * 4 + 2) * SHICAP + i];
        for (int i = tid; i < c3; i += 256) keys[off3 + i] = wsk[(size_t)(ch * 4 + 3) * SHICAP + i];
        __syncthreads();

        unsigned long long mine0 = (tid < n)       ? keys[tid]       : 0ull;
        unsigned long long mine1 = (tid + 256 < n) ? keys[tid + 256] : 0ull;
        unsigned long long mine2 = (tid + 512 < n) ? keys[tid + 512] : 0ull;
        int r0 = 0, r1 = 0, r2 = 0;
        for (int j = 0; j < n; ++j) {
            unsigned long long kj = keys[j];     // broadcast read, conflict-free
            r0 += (kj > mine0) ? 1 : 0;
            r1 += (kj > mine1) ? 1 : 0;
            r2 += (kj > mine2) ? 1 : 0;
        }
        if (tid < n       && r0 < PPK) sel[r0] = mine0;
        if (tid + 256 < n && r1 < PPK) sel[r1] = mine1;
        if (tid + 512 < n && r2 < PPK) sel[r2] = mine2;
        __syncthreads();
    } else {
        // ---- FALLBACK: full >0.1 rescan + butterfly selection (validated) ----
        __syncthreads();                       // cnt init visible
        for (int c = tid; c < HW / 4; c += 256) {
            int y  = c / CGW;
            int cg = c - y * CGW;
            int x0 = cg * 4;
            int yu = (y > 0) ? y - 1 : 0;
            int yd = (y < HH - 1) ? y + 1 : HH - 1;
            const float* rc = hp + y  * WW + x0;
            const float* ru = hp + yu * WW + x0;
            const float* rd = hp + yd * WW + x0;
            float4 vc = *(const float4*)rc;
            float4 vu = *(const float4*)ru;
            float4 vd = *(const float4*)rd;
            int offL = (x0 > 0) ? -1 : 0;
            int offR = (x0 + 4 < WW) ? 4 : 3;
            float lc  = rc[offL], lu  = ru[offL], ld  = rd[offL];
            float rcx = rc[offR], rux = ru[offR], rdx = rd[offR];

            float mu0 = max3f(lu, vu.x, vu.y), mu1 = max3f(vu.x, vu.y, vu.z);
            float mu2 = max3f(vu.y, vu.z, vu.w), mu3 = max3f(vu.z, vu.w, rux);
            float mc0 = max3f(lc, vc.x, vc.y), mc1 = max3f(vc.x, vc.y, vc.z);
            float mc2 = max3f(vc.y, vc.z, vc.w), mc3 = max3f(vc.z, vc.w, rcx);
            float md0 = max3f(ld, vd.x, vd.y), md1 = max3f(vd.x, vd.y, vd.z);
            float md2 = max3f(vd.y, vd.z, vd.w), md3 = max3f(vd.z, vd.w, rdx);

            float nm0 = max3f(mu0, mc0, md0);
            float nm1 = max3f(mu1, mc1, md1);
            float nm2 = max3f(mu2, mc2, md2);
            float nm3 = max3f(mu3, mc3, md3);

            bool pk0 = (vc.x == nm0) && (vc.x > 0.1f);
            bool pk1 = (vc.y == nm1) && (vc.y > 0.1f);
            bool pk2 = (vc.z == nm2) && (vc.z > 0.1f);
            bool pk3 = (vc.w == nm3) && (vc.w > 0.1f);

            unsigned long long b0 = __ballot(pk0);
            unsigned long long b1 = __ballot(pk1);
            unsigned long long b2 = __ballot(pk2);
            unsigned long long b3 = __ballot(pk3);
            int d0 = __popcll(b0), d1 = __popcll(b1), d2 = __popcll(b2), d3 = __popcll(b3);
            int tot = d0 + d1 + d2 + d3;
            int base = 0;
            if (lane == 0 && tot > 0) base = atomicAdd(&cnt, tot);
            base = __shfl(base, 0);

            int idx0 = y * WW + x0;
            if (pk0) { int s = base + __popcll(b0 & ltmask); if (s < CAP)
                keys[s] = ((unsigned long long)__float_as_uint(vc.x) << 32) | (unsigned long long)(0xFFFFFFFFu - (unsigned)(idx0 + 0)); }
            if (pk1) { int s = base + d0 + __popcll(b1 & ltmask); if (s < CAP)
                keys[s] = ((unsigned long long)__float_as_uint(vc.y) << 32) | (unsigned long long)(0xFFFFFFFFu - (unsigned)(idx0 + 1)); }
            if (pk2) { int s = base + d0 + d1 + __popcll(b2 & ltmask); if (s < CAP)
                keys[s] = ((unsigned long long)__float_as_uint(vc.z) << 32) | (unsigned long long)(0xFFFFFFFFu - (unsigned)(idx0 + 2)); }
            if (pk3) { int s = base + d0 + d1 + d2 + __popcll(b3 & ltmask); if (s < CAP)
                keys[s] = ((unsigned long long)__float_as_uint(vc.w) << 32) | (unsigned long long)(0xFFFFFFFFu - (unsigned)(idx0 + 3)); }
        }
        __syncthreads();

        const int m = (cnt < CAP) ? cnt : CAP;
        unsigned long long k[16];
        {
            int base0 = wave * 1024 + lane;
            #pragma unroll
            for (int i = 0; i < 16; ++i) {
                int p = base0 + i * 64;
                k[i] = (p < m) ? keys[p] : 0ull;
            }
        }
        for (int r = 0; r < PPK; ++r) {
            unsigned long long best = 0ull;
            #pragma unroll
            for (int i = 0; i < 16; ++i) best = umax64(best, k[i]);
            #pragma unroll
            for (int off = 1; off < 64; off <<= 1)
                best = umax64(best, (unsigned long long)__shfl_xor((long long)best, off));
            if (best != 0ull) {
                #pragma unroll
                for (int i = 0; i < 16; ++i)
                    if (k[i] == best) k[i] = 0ull;
            }
            if (lane == 0) sel4[wave * PPK + r] = best;
        }
        __syncthreads();
        if (wave == 0) {
            unsigned long long m0 = (lane < 4 * PPK) ? sel4[lane] : 0ull;
            unsigned long long m1 = (lane + 64 < 4 * PPK) ? sel4[lane + 64] : 0ull;
            for (int r = 0; r < PPK; ++r) {
                unsigned long long best = umax64(m0, m1);
                #pragma unroll
                for (int off = 1; off < 64; off <<= 1)
                    best = umax64(best, (unsigned long long)__shfl_xor((long long)best, off));
                if (best != 0ull) {
                    if (m0 == best) m0 = 0ull;
                    else if (m1 == best) m1 = 0ull;
                }
                if (lane == 0) sel[r] = best;
            }
        }
        __syncthreads();
    }

    // ---- emit peaks with subpixel refinement (bit-identical to validated) ----
    if (tid < PPK) {
        unsigned long long g = sel[tid];
        float px = 0.0f, py = 0.0f, sc = 0.0f;
        if (g != 0ull) {
            float v = __uint_as_float((unsigned int)(g >> 32));
            int idx = (int)(0xFFFFFFFFu - (unsigned int)(g & 0xFFFFFFFFull));
            int y = idx / WW;
            int x = idx - y * WW;
            float dx = 0.0f, dy = 0.0f;
            if (x > 0 && x < WW - 1 && y > 0 && y < HH - 1) {
                float r_ = hp[y * WW + x + 1];
                float l_ = hp[y * WW + x - 1];
                float dn = hp[(y + 1) * WW + x];
                float up = hp[(y - 1) * WW + x];
                float dx_raw = 0.5f * (r_ - l_);
                float dy_raw = 0.5f * (dn - up);
                float dxx = __fsub_rn(__fadd_rn(r_, l_), 2.0f * v);
                float dyy = __fsub_rn(__fadd_rn(dn, up), 2.0f * v);
                dx = (fabsf(dxx) > 1e-6f) ? (dx_raw / (-dxx)) : dx_raw;
                dy = (fabsf(dyy) > 1e-6f) ? (dy_raw / (-dyy)) : dy_raw;
            }
            px = __fadd_rn((float)x, dx);
            py = __fadd_rn((float)y, dy);
            sc = v;
        }
        float* o = out + ((size_t)ch * PPK + tid) * 3;
        o[0] = px;
        o[1] = py;
        o[2] = sc;
    }
}

// ---------------------------------------------------------------------------
// Fused fallback peaks kernel (r6, validated) — used if ws too small.
// ---------------------------------------------------------------------------
static constexpr int FHICAP = 512;
__global__ __launch_bounds__(512, 4) void peaks_fused(const float* __restrict__ heat,
                                                      float* __restrict__ out)
{
    const int ch = blockIdx.x;
    const float* hp = heat + (size_t)ch * HW;

    __shared__ unsigned long long keys[CAP];
    __shared__ unsigned long long hikeys[FHICAP];
    __shared__ unsigned long long sel8[8 * PPK];
    __shared__ unsigned long long sel[PPK];
    __shared__ int cnt;
    __shared__ int hcnt;

    const int tid  = threadIdx.x;
    const int lane = tid & 63;
    const int wave = tid >> 6;
    const unsigned long long ltmask = ((unsigned long long)1 << lane) - 1ull;

    if (tid == 0) { cnt = 0; hcnt = 0; }
    __syncthreads();

    for (int c = tid; c < HW / 4; c += 512) {
        int y  = c / CGW;
        int cg = c - y * CGW;
        int x0 = cg * 4;
        int yu = (y > 0) ? y - 1 : 0;
        int yd = (y < HH - 1) ? y + 1 : HH - 1;
        const float* rc = hp + y  * WW + x0;
        const float* ru = hp + yu * WW + x0;
        const float* rd = hp + yd * WW + x0;
        float4 vc = *(const float4*)rc;
        float4 vu = *(const float4*)ru;
        float4 vd = *(const float4*)rd;
        int offL = (x0 > 0) ? -1 : 0;
        int offR = (x0 + 4 < WW) ? 4 : 3;
        float lc  = rc[offL], lu  = ru[offL], ld  = rd[offL];
        float rcx = rc[offR], rux = ru[offR], rdx = rd[offR];
        float mu0 = max3f(lu, vu.x, vu.y), mu1 = max3f(vu.x, vu.y, vu.z);
        float mu2 = max3f(vu.y, vu.z, vu.w), mu3 = max3f(vu.z, vu.w, rux);
        float mc0 = max3f(lc, vc.x, vc.y), mc1 = max3f(vc.x, vc.y, vc.z);
        float mc2 = max3f(vc.y, vc.z, vc.w), mc3 = max3f(vc.z, vc.w, rcx);
        float md0 = max3f(ld, vd.x, vd.y), md1 = max3f(vd.x, vd.y, vd.z);
        float md2 = max3f(vd.y, vd.z, vd.w), md3 = max3f(vd.z, vd.w, rdx);
        float nm0 = max3f(mu0, mc0, md0);
        float nm1 = max3f(mu1, mc1, md1);
        float nm2 = max3f(mu2, mc2, md2);
        float nm3 = max3f(mu3, mc3, md3);
        bool pk0 = (vc.x == nm0) && (vc.x > 0.1f);
        bool pk1 = (vc.y == nm1) && (vc.y > 0.1f);
        bool pk2 = (vc.z == nm2) && (vc.z > 0.1f);
        bool pk3 = (vc.w == nm3) && (vc.w > 0.1f);
        int idx0 = y * WW + x0;
        unsigned long long key0 = ((unsigned long long)__float_as_uint(vc.x) << 32) | (unsigned long long)(0xFFFFFFFFu - (unsigned)(idx0 + 0));
        unsigned long long key1 = ((unsigned long long)__float_as_uint(vc.y) << 32) | (unsigned long long)(0xFFFFFFFFu - (unsigned)(idx0 + 1));
        unsigned long long key2 = ((unsigned long long)__float_as_uint(vc.z) << 32) | (unsigned long long)(0xFFFFFFFFu - (unsigned)(idx0 + 2));
        unsigned long long key3 = ((unsigned long long)__float_as_uint(vc.w) << 32) | (unsigned long long)(0xFFFFFFFFu - (unsigned)(idx0 + 3));
        {
            unsigned long long b0 = __ballot(pk0);
            unsigned long long b1 = __ballot(pk1);
            unsigned long long b2 = __ballot(pk2);
            unsigned long long b3 = __ballot(pk3);
            int c0 = __popcll(b0), c1 = __popcll(b1), c2 = __popcll(b2), c3 = __popcll(b3);
            int tot = c0 + c1 + c2 + c3;
            int base = 0;
            if (lane == 0 && tot > 0) base = atomicAdd(&cnt, tot);
            base = __shfl(base, 0);
            if (pk0) { int s = base + __popcll(b0 & ltmask); if (s < CAP) keys[s] = key0; }
            if (pk1) { int s = base + c0 + __popcll(b1 & ltmask); if (s < CAP) keys[s] = key1; }
            if (pk2) { int s = base + c0 + c1 + __popcll(b2 & ltmask); if (s < CAP) keys[s] = key2; }
            if (pk3) { int s = base + c0 + c1 + c2 + __popcll(b3 & ltmask); if (s < CAP) keys[s] = key3; }
        }
        {
            bool h0 = pk0 && (vc.x > HITHR);
            bool h1 = pk1 && (vc.y > HITHR);
            bool h2 = pk2 && (vc.z > HITHR);
            bool h3 = pk3 && (vc.w > HITHR);
            unsigned long long b0 = __ballot(h0);
            unsigned long long b1 = __ballot(h1);
            unsigned long long b2 = __ballot(h2);
            unsigned long long b3 = __ballot(h3);
            int c0 = __popcll(b0), c1 = __popcll(b1), c2 = __popcll(b2), c3 = __popcll(b3);
            int tot = c0 + c1 + c2 + c3;
            if (tot > 0) {
                int base = 0;
                if (lane == 0) base = atomicAdd(&hcnt, tot);
                base = __shfl(base, 0);
                if (h0) { int s = base + __popcll(b0 & ltmask); if (s < FHICAP) hikeys[s] = key0; }
                if (h1) { int s = base + c0 + __popcll(b1 & ltmask); if (s < FHICAP) hikeys[s] = key1; }
                if (h2) { int s = base + c0 + c1 + __popcll(b2 & ltmask); if (s < FHICAP) hikeys[s] = key2; }
                if (h3) { int s = base + c0 + c1 + c2 + __popcll(b3 & ltmask); if (s < FHICAP) hikeys[s] = key3; }
            }
        }
    }
    __syncthreads();

    const int hn = hcnt;
    if (hn >= PPK && hn <= FHICAP) {
        if (wave == 0) {
            unsigned long long k[8];
            #pragma unroll
            for (int i = 0; i < 8; ++i) {
                int p = lane + i * 64;
                k[i] = (p < hn) ? hikeys[p] : 0ull;
            }
            for (int r = 0; r < PPK; ++r) {
                unsigned long long best = 0ull;
                #pragma unroll
                for (int i = 0; i < 8; ++i) best = umax64(best, k[i]);
                #pragma unroll
                for (int off = 1; off < 64; off <<= 1)
                    best = umax64(best, (unsigned long long)__shfl_xor((long long)best, off));
                if (best != 0ull) {
                    #pragma unroll
                    for (int i = 0; i < 8; ++i)
                        if (k[i] == best) k[i] = 0ull;
                }
                if (lane == 0) sel[r] = best;
            }
        }
    } else {
        const int n = (cnt < CAP) ? cnt : CAP;
        unsigned long long k[8];
        {
            int base0 = wave * 512 + lane;
            #pragma unroll
            for (int i = 0; i < 8; ++i) {
                int p = base0 + i * 64;
                k[i] = (p < n) ? keys[p] : 0ull;
            }
        }
        for (int r = 0; r < PPK; ++r) {
            unsigned long long best = 0ull;
            #pragma unroll
            for (int i = 0; i < 8; ++i) best = umax64(best, k[i]);
            #pragma unroll
            for (int off = 1; off < 64; off <<= 1)
                best = umax64(best, (unsigned long long)__shfl_xor((long long)best, off));
            if (best != 0ull) {
                #pragma unroll
                for (int i = 0; i < 8; ++i)
                    if (k[i] == best) k[i] = 0ull;
            }
            if (lane == 0) sel8[wave * PPK + r] = best;
        }
        __syncthreads();
        if (wave == 0) {
            unsigned long long m[4];
            #pragma unroll
            for (int i = 0; i < 4; ++i) {
                int p = lane + i * 64;
                m[i] = (p < 8 * PPK) ? sel8[p] : 0ull;
            }
            for (int r = 0; r < PPK; ++r) {
                unsigned long long best = umax64(umax64(m[0], m[1]), umax64(m[2], m[3]));
                #pragma unroll
                for (int off = 1; off < 64; off <<= 1)
                    best = umax64(best, (unsigned long long)__shfl_xor((long long)best, off));
                if (best != 0ull) {
                    #pragma unroll
                    for (int i = 0; i < 4; ++i)
                        if (m[i] == best) m[i] = 0ull;
                }
                if (lane == 0) sel[r] = best;
            }
        }
    }
    __syncthreads();

    if (tid < PPK) {
        unsigned long long g = sel[tid];
        float px = 0.0f, py = 0.0f, sc = 0.0f;
        if (g != 0ull) {
            float v = __uint_as_float((unsigned int)(g >> 32));
            int idx = (int)(0xFFFFFFFFu - (unsigned int)(g & 0xFFFFFFFFull));
            int y = idx / WW;
            int x = idx - y * WW;
            float dx = 0.0f, dy = 0.0f;
            if (x > 0 && x < WW - 1 && y > 0 && y < HH - 1) {
                float r_ = hp[y * WW + x + 1];
                float l_ = hp[y * WW + x - 1];
                float dn = hp[(y + 1) * WW + x];
                float up = hp[(y - 1) * WW + x];
                float dx_raw = 0.5f * (r_ - l_);
                float dy_raw = 0.5f * (dn - up);
                float dxx = __fsub_rn(__fadd_rn(r_, l_), 2.0f * v);
                float dyy = __fsub_rn(__fadd_rn(dn, up), 2.0f * v);
                dx = (fabsf(dxx) > 1e-6f) ? (dx_raw / (-dxx)) : dx_raw;
                dy = (fabsf(dyy) > 1e-6f) ? (dy_raw / (-dyy)) : dy_raw;
            }
            px = __fadd_rn((float)x, dx);
            py = __fadd_rn((float)y, dy);
            sc = v;
        }
        float* o = out + ((size_t)ch * PPK + tid) * 3;
        o[0] = px;
        o[1] = py;
        o[2] = sc;
    }
}

// ---------------------------------------------------------------------------
// Kernel 2: PAF connection scoring.
// Counted-vmcnt two-barrier pipeline (no vmcnt(0) drain in the main loop).
// Per stage each wave issues exactly 3 global_load_lds (wave 0: 4). At stage
// top we issue stage q+1's loads, then wait vmcnt(3|4) = "my stage-q loads
// have landed", then s_barrier (cross-wave), gather, s_barrier (reads of
// buf[cur] done -> next iter may overwrite).
// Deadlock audit: 16 unconditional s_barrier per wave (1 prologue + 2*7 + 1),
// identical across waves; vmcnt waits always satisfiable (outstanding >= N).
// WAR audit: gather lgkm-waits pinned before end barrier by sched_barrier(0);
// overwriting DMA issued only after all waves pass it.
// ---------------------------------------------------------------------------
__global__ __launch_bounds__(512, 4) void conn_kernel(const float* __restrict__ paf,
                                                      const float* __restrict__ peaks,
                                                      float* __restrict__ conn)
{
    const int bl = blockIdx.x;
    const int b  = bl / LL;
    const int l  = bl - b * LL;

    __shared__ float buf[2][QCNT];
    __shared__ float As[PPK * 3];
    __shared__ float Bs[PPK * 3];

    const int tid  = threadIdx.x;
    const int lane = tid & 63;
    const int wave = tid >> 6;

    // (1) As/Bs global->LDS FIRST: the compiler's vmcnt wait before the
    // ds_write lands before the async copies are issued, so it does not
    // drain them.
    {
        const float* pa = peaks + (((size_t)b * KJ) + d_ska[l]) * (PPK * 3);
        const float* pb = peaks + (((size_t)b * KJ) + d_skb[l]) * (PPK * 3);
        if (tid < PPK * 3)            As[tid] = pa[tid];
        else if (tid < 2 * PPK * 3)   Bs[tid - PPK * 3] = pb[tid - PPK * 3];
    }
    __builtin_amdgcn_sched_barrier(0);

    const float*  src  = paf + (((size_t)b * (2 * LL)) + 2 * l) * HW;
    const float4* src4 = (const float4*)src;

    // (2) issue buf[0] prefetch — stays in flight across the next barrier
    {
        float4* b4 = (float4*)buf[0];
        #pragma unroll
        for (int c = 0; c < 3; ++c)
            async_copy16(src4 + c * 512 + tid, b4 + c * 512 + wave * 64);
        if (wave == 0)
            async_copy16(src4 + 1536 + lane, b4 + 1536);
    }
    // (3) make As/Bs visible WITHOUT draining vmcnt
    asm volatile("s_waitcnt lgkmcnt(0)" ::: "memory");
    __builtin_amdgcn_s_barrier();
    __builtin_amdgcn_sched_barrier(0);

    const bool active = (tid < HALFP);
    const int p0 = active ? tid : (NPAIR - 1);
    const int p1 = active ? (tid + HALFP) : (NPAIR - 1);

    int   lin[2][SS];
    float accv[2][SS];
    float vxp[2], vyp[2], sap[2], sbp[2];

    #pragma unroll
    for (int q = 0; q < 2; ++q) {
        int p = (q == 0) ? p0 : p1;
        int i = p / PPK;
        int j = p - i * PPK;
        float ax = As[i * 3 + 0], ay = As[i * 3 + 1], sa = As[i * 3 + 2];
        float bx = Bs[j * 3 + 0], by = Bs[j * 3 + 1], sb = Bs[j * 3 + 2];
        float dxl = __fsub_rn(bx, ax);
        float dyl = __fsub_rn(by, ay);
        float nsq = __fadd_rn(__fmul_rn(dxl, dxl), __fmul_rn(dyl, dyl));
        float nrm = __fadd_rn(sqrtf(nsq), 1e-8f);
        vxp[q] = dxl / nrm;
        vyp[q] = dyl / nrm;
        sap[q] = sa;
        sbp[q] = sb;
        #pragma unroll
        for (int s = 0; s < SS; ++s) {
            float t  = d_ts[s];
            float xs = __fadd_rn(ax, __fmul_rn(t, dxl));
            float ys = __fadd_rn(ay, __fmul_rn(t, dyl));
            float rx = rintf(xs);
            float ry = rintf(ys);
            rx = fminf(fmaxf(rx, 0.0f), (float)(WW - 1));
            ry = fminf(fmaxf(ry, 0.0f), (float)(HH - 1));
            lin[q][s] = (int)ry * WW + (int)rx;
        }
    }

    for (int qq = 0; qq < 8; ++qq) {
        const int cur = qq & 1;
        if (qq < 7) {
            const int nq = qq + 1;
            const float4* s4 = (const float4*)(src + (size_t)(nq >> 2) * HW + (nq & 3) * QCNT);
            float4* b4 = (float4*)buf[1 - cur];
            #pragma unroll
            for (int c = 0; c < 3; ++c)
                async_copy16(s4 + c * 512 + tid, b4 + c * 512 + wave * 64);
            if (wave == 0)
                async_copy16(s4 + 1536 + lane, b4 + 1536);
            __builtin_amdgcn_sched_barrier(0);
            // wait only for MY stage-qq loads (3 or 4 issued last iter);
            // the 3|4 just issued for stage qq+1 remain in flight.
            if (wave == 0) asm volatile("s_waitcnt vmcnt(4)" ::: "memory");
            else           asm volatile("s_waitcnt vmcnt(3)" ::: "memory");
        } else {
            asm volatile("s_waitcnt vmcnt(0)" ::: "memory");
        }
        __builtin_amdgcn_s_barrier();          // cross-wave: stage-qq fully in LDS
        __builtin_amdgcn_sched_barrier(0);

        const int comp = qq >> 2;
        const int lo   = (qq & 3) * QCNT;
        #pragma unroll
        for (int q = 0; q < 2; ++q) {
            #pragma unroll
            for (int s = 0; s < SS; ++s) {
                int lrel = lin[q][s] - lo;
                if ((unsigned)lrel < (unsigned)QCNT) {
                    float v = buf[cur][lrel];
                    if (comp == 0) accv[q][s] = __fmul_rn(v, vxp[q]);
                    else           accv[q][s] = __fadd_rn(accv[q][s], __fmul_rn(v, vyp[q]));
                }
            }
        }
        __builtin_amdgcn_sched_barrier(0);
        if (qq < 7) __builtin_amdgcn_s_barrier();  // reads done -> next iter may overwrite
    }

    if (active) {
        #pragma unroll
        for (int q = 0; q < 2; ++q) {
            int p = (q == 0) ? p0 : p1;
            int cntc = 0;
            #pragma unroll
            for (int s = 0; s < SS; ++s)
                if (accv[q][s] > 0.05f) ++cntc;
            float s01 = __fadd_rn(accv[q][0], accv[q][1]);
            float s23 = __fadd_rn(accv[q][2], accv[q][3]);
            float s45 = __fadd_rn(accv[q][4], accv[q][5]);
            float s67 = __fadd_rn(accv[q][6], accv[q][7]);
            float sum = __fadd_rn(__fadd_rn(s01, s23), __fadd_rn(s45, s67));
            sum = __fadd_rn(sum, accv[q][8]);
            sum = __fadd_rn(sum, accv[q][9]);
            float mean = sum / 10.0f;
            bool va = sap[q] > 0.1f;
            bool vb = sbp[q] > 0.1f;
            bool cond = (mean > 0.0f) && (cntc >= 9) && va && vb;
            float val = 0.0f;
            if (cond) val = __fadd_rn(mean, __fmul_rn(0.5f, __fadd_rn(sap[q], sbp[q])));
            conn[(size_t)bl * NPAIR + p] = val;
        }
    }
}

extern "C" void kernel_launch(void* const* d_in, const int* in_sizes, int n_in,
                              void* d_out, int out_size, void* d_ws, size_t ws_size,
                              hipStream_t stream)
{
    const float* heat = (const float*)d_in[0];   // [32,17,160,160]
    const float* paf  = (const float*)d_in[1];   // [32,38,160,160]
    float* out = (float*)d_out;

    float* peaks_out = out;                                   // 48960
    float* conn_out  = out + (size_t)BATCH * KJ * PPK * 3;    // 547200

    if (ws_size >= WS_NEED) {
        unsigned long long* wsk = (unsigned long long*)d_ws;
        int* wsc = (int*)((char*)d_ws + WS_KEYS_BYTES);
        hipLaunchKernelGGL(peaks_scan_hi, dim3(NCH * NSTR), dim3(256), 0, stream,
                           heat, wsk, wsc);
        hipLaunchKernelGGL(peaks_select, dim3(NCH), dim3(256), 0, stream,
                           heat, wsk, wsc, peaks_out);
    } else {
        hipLaunchKernelGGL(peaks_fused, dim3(NCH), dim3(512), 0, stream,
                           heat, peaks_out);
    }
    hipLaunchKernelGGL(conn_kernel, dim3(BATCH * LL), dim3(512), 0, stream,
                       paf, peaks_out, conn_out);
}